// Round 17
// baseline (119.592 us; speedup 1.0000x reference)
//
#include <hip/hip_runtime.h>

// One timestep of the AI4CFD semicircle-cylinder NS solver.
// Grid: interior NY x NX = 160 x 6600, padded PY x PX = 162 x 6602.
// Round 17: round-16 (PASSING, 119.5us) with ONE change:
// __launch_bounds__(64, 1) on jacobi_reg. r15 counters showed VGPR_Count=72
// against a live set of p[]+rq[] > 80 floats -> allocator was capping regs
// (occupancy heuristic), spilling to scratch and re-serializing the sweep.
// min-waves-per-EU=1 lets it use up to 512 VGPRs; we only need ~1.1/SIMD.

namespace {
constexpr int NY = 160, NX = 6600, PY = 162, PX = 6602;
constexpr int NI = NY * NX;   // 1,056,000
constexpr int NP = PY * PX;   // 1,069,524
constexpr float DT  = 0.005f;
constexpr float NU  = 0.01f;          // 1/RE
constexpr float AT  = 1.0f / 70.0f;   // 1/(RE*PR)

constexpr int JK   = 8;               // iterations per stage
constexpr int HALO = 8;
constexpr int JCH  = 20;              // core rows per wave
constexpr int JCW  = 48;              // core cols per wave (64 - 2*HALO)
constexpr int JR   = JCH + 2 * HALO;  // 36 register rows
constexpr int JTX  = (NX + JCW - 1) / JCW;  // 138
constexpr int JTY  = NY / JCH;        // 8
constexpr int JWAVES = JTX * JTY;     // 1104
constexpr int RN   = HALO;            // row where gy==0 can occur (ty==0)
constexpr int RS   = JR - HALO - 1;   // row where gy==NY-1 occurs (ty==JTY-1)
}

// Brinkman penalization field: semicircle at (x=1800, y=80), R=20, x>=1800.
__device__ __forceinline__ float sigma_at(int y, int x) {
    int ddx = x - 1800, ddy = y - 80;
    return ((ddx * ddx + ddy * ddy <= 400) && (x >= 1800)) ? 1.0e6f : 0.0f;
}

// ---- stencil weights ----
__device__ __forceinline__ float cxv(const float r[3][3]) {   // w_xadv
    return (r[0][0] - r[0][2] + 4.0f * (r[1][0] - r[1][2]) + r[2][0] - r[2][2])
           * (1.0f / 12.0f);
}
__device__ __forceinline__ float cyv(const float r[3][3]) {   // w_yadv
    return (r[0][0] + 4.0f * r[0][1] + r[0][2]
            - r[2][0] - 4.0f * r[2][1] - r[2][2]) * (1.0f / 12.0f);
}
__device__ __forceinline__ float cdv(const float r[3][3]) {   // w_diff
    return (r[0][0] + r[0][1] + r[0][2]
            + r[1][0] - 8.0f * r[1][1] + r[1][2]
            + r[2][0] + r[2][1] + r[2][2]) * (1.0f / 3.0f);
}

// g9 / g9p gathers for the aux kernels.
__device__ __forceinline__ void g9(const float* __restrict__ a, int y, int x,
                                   float lc, float r[3][3]) {
    int ym = max(y - 1, 0), yp = min(y + 1, NY - 1);
    int xp = min(x + 1, NX - 1);
    const float* r0 = a + (size_t)ym * NX;
    const float* r1 = a + (size_t)y  * NX;
    const float* r2 = a + (size_t)yp * NX;
    if (x == 0) { r[0][0] = lc; r[1][0] = lc; r[2][0] = lc; }
    else        { r[0][0] = r0[x-1]; r[1][0] = r1[x-1]; r[2][0] = r2[x-1]; }
    r[0][1] = r0[x]; r[0][2] = r0[xp];
    r[1][1] = r1[x]; r[1][2] = r1[xp];
    r[2][1] = r2[x]; r[2][2] = r2[xp];
}
__device__ __forceinline__ void g9p(const float* __restrict__ a, int y, int x,
                                    float r[3][3]) {
    int ym = max(y - 1, 0), yp = min(y + 1, NY - 1);
    int xm = max(x - 1, 0);
    bool rb = (x == NX - 1);
    const float* r0 = a + (size_t)ym * NX;
    const float* r1 = a + (size_t)y  * NX;
    const float* r2 = a + (size_t)yp * NX;
    r[0][0] = r0[xm]; r[0][1] = r0[x]; r[0][2] = rb ? 0.0f : r0[x+1];
    r[1][0] = r1[xm]; r[1][1] = r1[x]; r[1][2] = rb ? 0.0f : r1[x+1];
    r[2][0] = r2[xm]; r[2][1] = r2[x]; r[2][2] = rb ? 0.0f : r2[x+1];
}

// ---------------- aux kernels (unchanged, proven in rounds 1-3/7/9) ------------
__global__ void pred_k(const float* __restrict__ u, const float* __restrict__ v,
                       const float* __restrict__ T,
                       float* __restrict__ up, float* __restrict__ vp,
                       float* __restrict__ Tp, float* __restrict__ oTT) {
    int px = blockIdx.x * blockDim.x + threadIdx.x;
    int py = blockIdx.y;
    if (px >= PX) return;
    int y = py - 1, x = px - 1;
    int cy = min(max(y, 0), NY - 1), cx = min(max(x, 0), NX - 1);
    oTT[(size_t)py * PX + px] = (px == 0) ? 0.0f : T[(size_t)cy * NX + cx];
    if (y < 0 || y >= NY || x < 0 || x >= NX) return;
    float ru[3][3], rv[3][3], rt[3][3];
    g9(u, y, x, 1.5f, ru);
    g9(v, y, x, 0.0f, rv);
    g9(T, y, x, 0.0f, rt);
    float uav = ru[1][1], vav = rv[1][1];
    float sig = sigma_at(y, x);
    const float hdt = 0.5f * DT;
    float un = ru[1][1] + hdt * (uav * cxv(ru) + vav * cyv(ru) + NU * cdv(ru));
    float vn = rv[1][1] + hdt * (uav * cxv(rv) + vav * cyv(rv) + NU * cdv(rv));
    float Tn = rt[1][1] + hdt * (uav * cxv(rt) + vav * cyv(rt) + AT * cdv(rt));
    float den = 1.0f + hdt * sig;
    un /= den; vn /= den;
    if (sig > 0.0f) Tn = 1.0f;
    size_t i = (size_t)y * NX + x;
    up[i] = un; vp[i] = vn; Tp[i] = Tn;
}

__global__ void corr_k(const float* __restrict__ u, const float* __restrict__ v,
                       const float* __restrict__ T,
                       const float* __restrict__ up, const float* __restrict__ vp,
                       const float* __restrict__ Tp,
                       float* __restrict__ us, float* __restrict__ vs,
                       float* __restrict__ oT,
                       float* __restrict__ obuu, float* __restrict__ obvv,
                       float* __restrict__ obTT) {
    int px = blockIdx.x * blockDim.x + threadIdx.x;
    int py = blockIdx.y;
    if (px >= PX) return;
    int y = py - 1, x = px - 1;
    int cy = min(max(y, 0), NY - 1), cx = min(max(x, 0), NX - 1);
    size_t o = (size_t)py * PX + px, s = (size_t)cy * NX + cx;
    obuu[o] = (px == 0) ? 1.5f : up[s];
    obvv[o] = (px == 0) ? 0.0f : vp[s];
    obTT[o] = (px == 0) ? 0.0f : Tp[s];
    if (y < 0 || y >= NY || x < 0 || x >= NX) return;
    float ru[3][3], rv[3][3], rt[3][3];
    g9(up, y, x, 1.5f, ru);
    g9(vp, y, x, 0.0f, rv);
    g9(Tp, y, x, 0.0f, rt);
    float uav = ru[1][1], vav = rv[1][1];
    float sig = sigma_at(y, x);
    size_t i = (size_t)y * NX + x;
    float un = u[i] + DT * (uav * cxv(ru) + vav * cyv(ru) + NU * cdv(ru));
    float vn = v[i] + DT * (uav * cxv(rv) + vav * cyv(rv) + NU * cdv(rv));
    float Tn = T[i] + DT * (uav * cxv(rt) + vav * cyv(rt) + AT * cdv(rt));
    float den = 1.0f + DT * sig;
    un /= den; vn /= den;
    if (sig > 0.0f) Tn = 1.0f;
    us[i] = un; vs[i] = vn; oT[i] = Tn;
}

__global__ void rhsdiv_k(const float* __restrict__ us, const float* __restrict__ vs,
                         float* __restrict__ rhs,
                         float* __restrict__ ouus, float* __restrict__ ovvs) {
    int px = blockIdx.x * blockDim.x + threadIdx.x;
    int py = blockIdx.y;
    if (px >= PX) return;
    int y = py - 1, x = px - 1;
    int cy = min(max(y, 0), NY - 1), cx = min(max(x, 0), NX - 1);
    size_t o = (size_t)py * PX + px, s = (size_t)cy * NX + cx;
    ouus[o] = (px == 0) ? 1.5f : us[s];
    ovvs[o] = (px == 0) ? 0.0f : vs[s];
    if (y < 0 || y >= NY || x < 0 || x >= NX) return;
    float ru[3][3], rv[3][3];
    g9(us, y, x, 1.5f, ru);
    g9(vs, y, x, 0.0f, rv);
    rhs[(size_t)y * NX + x] = (cxv(ru) + cyv(rv)) * (1.0f / DT);
}

__global__ void proj2_k(const float* __restrict__ us, const float* __restrict__ vs,
                        const float* __restrict__ p,
                        float* __restrict__ un, float* __restrict__ vn,
                        float* __restrict__ opp) {
    int px = blockIdx.x * blockDim.x + threadIdx.x;
    int py = blockIdx.y;
    if (px >= PX) return;
    int y = py - 1, x = px - 1;
    int cy = min(max(y, 0), NY - 1);
    opp[(size_t)py * PX + px] =
        (px == PX - 1) ? 0.0f : p[(size_t)cy * NX + max(x, 0)];
    if (y < 0 || y >= NY || x < 0 || x >= NX) return;
    float rp[3][3];
    g9p(p, y, x, rp);
    float sig = sigma_at(y, x);
    float den = 1.0f + DT * sig;
    size_t i = (size_t)y * NX + x;
    un[i] = (us[i] + cxv(rp) * DT) / den;
    vn[i] = (vs[i] + cyv(rp) * DT) / den;
}

// ---------------- register-resident Jacobi (lean sweep) ----------------------
// Whole-wave DPP neighbor fetch (correctness-proven rounds 10/14):
//   wave_shr:1 (0x138): lane i <- lane i-1 (WEST); lane 0 keeps old(=self)
//   wave_shl:1 (0x130): lane i <- lane i+1 (EAST); lane 63 keeps old(=self)
__device__ __forceinline__ float dpp_west64(float x) {
    int i = __float_as_int(x);
    return __int_as_float(__builtin_amdgcn_update_dpp(i, i, 0x138, 0xF, 0xF, false));
}
__device__ __forceinline__ float dpp_east64(float x) {
    int i = __float_as_int(x);
    return __int_as_float(__builtin_amdgcn_update_dpp(i, i, 0x130, 0xF, 0xF, false));
}

// One Jacobi sweep. rq[] is PRE-SCALED by 0.375. Update:
//   p' = 0.125*(sum9 - p) + rq375. Residual (EMIT) = (p - p')*8/3.
// N/S domain clamp: wave-uniform cs[] fix-up. W/E lane clamp: edge tiles only.
template <bool EDGE, bool EMIT>
__device__ __forceinline__ void jsweep(float (&p)[JR], const float (&rq)[JR - 2],
                                       bool fixN, bool fixS,
                                       bool wb, bool eb, int gy0, int gx,
                                       bool stp, float* __restrict__ res) {
    float cs[JR];
#pragma unroll
    for (int r = 0; r < JR; ++r) {
        float c = p[r];
        float w = dpp_west64(c);
        float e = dpp_east64(c);
        if (EDGE) {
            w = wb ? c : w;     // gx==0: west neighbor = self (edge clamp)
            e = eb ? 0.0f : e;  // gx==NX-1: east neighbor = 0 (outlet pad)
        }
        cs[r] = w + c + e;
    }
    if (fixN) cs[RN - 1] = cs[RN];
    if (fixS) cs[RS + 1] = cs[RS];
#pragma unroll
    for (int r = 1; r < JR - 1; ++r) {
        float s  = cs[r - 1] + cs[r] + cs[r + 1] - p[r];
        float pn = fmaf(0.125f, s, rq[r - 1]);
        if (EMIT) {
            if (r >= HALO && r < HALO + JCH && stp)
                res[(size_t)(gy0 + r) * NX + gx] = (p[r] - pn) * (8.0f / 3.0f);
        }
        p[r] = pn;
    }
}

// One full stage: load register tile from src, JK sweeps, store core to dst.
template <bool EDGE>
__device__ __forceinline__ void jstage_reg(const float* __restrict__ src,
                                           float* __restrict__ dst,
                                           float* __restrict__ res,
                                           const float (&rq)[JR - 2],
                                           bool fixN, bool fixS,
                                           int gy0, int gx, int cgx,
                                           bool wb, bool eb, bool stp) {
    float p[JR];
#pragma unroll
    for (int r = 0; r < JR; ++r) {
        int cy = min(max(gy0 + r, 0), NY - 1);
        p[r] = src[(size_t)cy * NX + cgx];
    }
#pragma unroll 1
    for (int j = 0; j < JK - 1; ++j)
        jsweep<EDGE, false>(p, rq, fixN, fixS, wb, eb, gy0, gx, stp, nullptr);
    if (res) jsweep<EDGE, true>(p, rq, fixN, fixS, wb, eb, gy0, gx, stp, res);
    else     jsweep<EDGE, false>(p, rq, fixN, fixS, wb, eb, gy0, gx, stp, nullptr);
    if (stp) {
#pragma unroll
        for (int r = HALO; r < HALO + JCH; ++r)
            dst[(size_t)(gy0 + r) * NX + gx] = p[r];
    }
}

// min-waves-per-EU = 1: allow up to 512 VGPRs so p[]+rq[]+cs[] stay in
// registers (r15 showed VGPR_Count=72 < live set -> scratch spill).
__global__ __launch_bounds__(64, 1)
void jacobi_reg(const float* __restrict__ src, const float* __restrict__ rhs,
                float* __restrict__ dst, float* __restrict__ res) {
    const int wid = blockIdx.x;               // one 64-lane wave per block
    const int tx = wid % JTX, ty = wid / JTX;
    const int lane = threadIdx.x;             // 0..63
    const int gx = tx * JCW - HALO + lane;    // this lane's column
    const int gy0 = ty * JCH - HALO;          // tile top row
    const int cgx = min(max(gx, 0), NX - 1);  // clamped load column
    const bool wb = (gx == 0);                // west domain edge (clamp)
    const bool eb = (gx == NX - 1);           // east domain edge (outlet 0)
    const bool stp = (lane >= HALO) && (lane < HALO + JCW) && (gx < NX);
    const bool fixN = (ty == 0), fixS = (ty == JTY - 1);

    float rq[JR - 2];                          // 0.375 * rhs (pre-scaled)
#pragma unroll
    for (int r = 1; r < JR - 1; ++r) {
        int cy = min(max(gy0 + r, 0), NY - 1);
        rq[r - 1] = 0.375f * rhs[(size_t)cy * NX + cgx];
    }
    if (tx == 0 || tx == JTX - 1)
        jstage_reg<true>(src, dst, res, rq, fixN, fixS, gy0, gx, cgx, wb, eb, stp);
    else
        jstage_reg<false>(src, dst, res, rq, fixN, fixS, gy0, gx, cgx, wb, eb, stp);
}

extern "C" void kernel_launch(void* const* d_in, const int* in_sizes, int n_in,
                              void* d_out, int out_size, void* d_ws, size_t ws_size,
                              hipStream_t stream) {
    const float* u = (const float*)d_in[0];
    const float* v = (const float*)d_in[1];
    const float* p = (const float*)d_in[2];
    const float* T = (const float*)d_in[3];

    float* out = (float*)d_out;
    float* o_u   = out;
    float* o_v   = out + (size_t)NI;
    float* o_p   = out + 2 * (size_t)NI;
    float* o_T   = out + 3 * (size_t)NI;
    float* o_uus = out + 4 * (size_t)NI;
    float* o_vvs = o_uus + (size_t)NP;
    float* o_pp  = o_uus + 2 * (size_t)NP;
    float* o_TT  = o_uus + 3 * (size_t)NP;
    float* o_buu = o_uus + 4 * (size_t)NP;
    float* o_bvv = o_uus + 5 * (size_t)NP;
    float* o_bTT = o_uus + 6 * (size_t)NP;
    float* o_res = o_uus + 7 * (size_t)NP;

    float* w  = (float*)d_ws;
    float* s_up  = w;                      // u_pred -> jacobi ping A
    float* s_vp  = w + (size_t)NI;         // v_pred -> jacobi ping B
    float* s_Tp  = w + 2 * (size_t)NI;     // T_pred -> rhs
    float* s_us  = w + 3 * (size_t)NI;     // u_star
    float* s_vs  = w + 4 * (size_t)NI;     // v_star
    float* s_rhs = s_Tp;
    float* pA = s_up;
    float* pB = s_vp;

    dim3 blk(256, 1, 1);
    dim3 gp((PX + 255) / 256, PY, 1);
    dim3 gj(JWAVES, 1, 1);
    dim3 bj(64, 1, 1);

    pred_k<<<gp, blk, 0, stream>>>(u, v, T, s_up, s_vp, s_Tp, o_TT);
    corr_k<<<gp, blk, 0, stream>>>(u, v, T, s_up, s_vp, s_Tp,
                                   s_us, s_vs, o_T, o_buu, o_bvv, o_bTT);
    rhsdiv_k<<<gp, blk, 0, stream>>>(s_us, s_vs, s_rhs, o_uus, o_vvs);

    // 40 Jacobi iterations = 5 stream-ordered launches x 8 register-resident
    jacobi_reg<<<gj, bj, 0, stream>>>(p,  s_rhs, pA,  nullptr);
    jacobi_reg<<<gj, bj, 0, stream>>>(pA, s_rhs, pB,  nullptr);
    jacobi_reg<<<gj, bj, 0, stream>>>(pB, s_rhs, pA,  nullptr);
    jacobi_reg<<<gj, bj, 0, stream>>>(pA, s_rhs, pB,  nullptr);
    jacobi_reg<<<gj, bj, 0, stream>>>(pB, s_rhs, o_p, o_res);

    proj2_k<<<gp, blk, 0, stream>>>(s_us, s_vs, o_p, o_u, o_v, o_pp);
}

// Round 18
// 110.983 us; speedup vs baseline: 1.0776x; 1.0776x over previous
//
#include <hip/hip_runtime.h>

// One timestep of the AI4CFD semicircle-cylinder NS solver.
// Grid: interior NY x NX = 160 x 6600, padded PY x PX = 162 x 6602.
// Round 18: round-16 (PASSING, 119.5us) with ONE change: JCH 20->32
// (JTY 8->5) so JWAVES = 690 <= 1024 SIMDs. With 1104 waves, 80 SIMDs ran
// TWO waves serially -> every stage paid 2x single-wave time. 690 waves
// = every SIMD runs at most one wave; stage ~= wave time.

namespace {
constexpr int NY = 160, NX = 6600, PY = 162, PX = 6602;
constexpr int NI = NY * NX;   // 1,056,000
constexpr int NP = PY * PX;   // 1,069,524
constexpr float DT  = 0.005f;
constexpr float NU  = 0.01f;          // 1/RE
constexpr float AT  = 1.0f / 70.0f;   // 1/(RE*PR)

constexpr int JK   = 8;               // iterations per stage
constexpr int HALO = 8;
constexpr int JCH  = 32;              // core rows per wave (160/32 = 5)
constexpr int JCW  = 48;              // core cols per wave (64 - 2*HALO)
constexpr int JR   = JCH + 2 * HALO;  // 48 register rows
constexpr int JTX  = (NX + JCW - 1) / JCW;  // 138
constexpr int JTY  = NY / JCH;        // 5
constexpr int JWAVES = JTX * JTY;     // 690  (<= 1024 SIMDs)
constexpr int RN   = HALO;            // row where gy==0 can occur (ty==0)
constexpr int RS   = JR - HALO - 1;   // row where gy==NY-1 occurs (ty==JTY-1)
}

// Brinkman penalization field: semicircle at (x=1800, y=80), R=20, x>=1800.
__device__ __forceinline__ float sigma_at(int y, int x) {
    int ddx = x - 1800, ddy = y - 80;
    return ((ddx * ddx + ddy * ddy <= 400) && (x >= 1800)) ? 1.0e6f : 0.0f;
}

// ---- stencil weights ----
__device__ __forceinline__ float cxv(const float r[3][3]) {   // w_xadv
    return (r[0][0] - r[0][2] + 4.0f * (r[1][0] - r[1][2]) + r[2][0] - r[2][2])
           * (1.0f / 12.0f);
}
__device__ __forceinline__ float cyv(const float r[3][3]) {   // w_yadv
    return (r[0][0] + 4.0f * r[0][1] + r[0][2]
            - r[2][0] - 4.0f * r[2][1] - r[2][2]) * (1.0f / 12.0f);
}
__device__ __forceinline__ float cdv(const float r[3][3]) {   // w_diff
    return (r[0][0] + r[0][1] + r[0][2]
            + r[1][0] - 8.0f * r[1][1] + r[1][2]
            + r[2][0] + r[2][1] + r[2][2]) * (1.0f / 3.0f);
}

// g9 / g9p gathers for the aux kernels.
__device__ __forceinline__ void g9(const float* __restrict__ a, int y, int x,
                                   float lc, float r[3][3]) {
    int ym = max(y - 1, 0), yp = min(y + 1, NY - 1);
    int xp = min(x + 1, NX - 1);
    const float* r0 = a + (size_t)ym * NX;
    const float* r1 = a + (size_t)y  * NX;
    const float* r2 = a + (size_t)yp * NX;
    if (x == 0) { r[0][0] = lc; r[1][0] = lc; r[2][0] = lc; }
    else        { r[0][0] = r0[x-1]; r[1][0] = r1[x-1]; r[2][0] = r2[x-1]; }
    r[0][1] = r0[x]; r[0][2] = r0[xp];
    r[1][1] = r1[x]; r[1][2] = r1[xp];
    r[2][1] = r2[x]; r[2][2] = r2[xp];
}
__device__ __forceinline__ void g9p(const float* __restrict__ a, int y, int x,
                                    float r[3][3]) {
    int ym = max(y - 1, 0), yp = min(y + 1, NY - 1);
    int xm = max(x - 1, 0);
    bool rb = (x == NX - 1);
    const float* r0 = a + (size_t)ym * NX;
    const float* r1 = a + (size_t)y  * NX;
    const float* r2 = a + (size_t)yp * NX;
    r[0][0] = r0[xm]; r[0][1] = r0[x]; r[0][2] = rb ? 0.0f : r0[x+1];
    r[1][0] = r1[xm]; r[1][1] = r1[x]; r[1][2] = rb ? 0.0f : r1[x+1];
    r[2][0] = r2[xm]; r[2][1] = r2[x]; r[2][2] = rb ? 0.0f : r2[x+1];
}

// ---------------- aux kernels (unchanged, proven in rounds 1-3/7/9) ------------
__global__ void pred_k(const float* __restrict__ u, const float* __restrict__ v,
                       const float* __restrict__ T,
                       float* __restrict__ up, float* __restrict__ vp,
                       float* __restrict__ Tp, float* __restrict__ oTT) {
    int px = blockIdx.x * blockDim.x + threadIdx.x;
    int py = blockIdx.y;
    if (px >= PX) return;
    int y = py - 1, x = px - 1;
    int cy = min(max(y, 0), NY - 1), cx = min(max(x, 0), NX - 1);
    oTT[(size_t)py * PX + px] = (px == 0) ? 0.0f : T[(size_t)cy * NX + cx];
    if (y < 0 || y >= NY || x < 0 || x >= NX) return;
    float ru[3][3], rv[3][3], rt[3][3];
    g9(u, y, x, 1.5f, ru);
    g9(v, y, x, 0.0f, rv);
    g9(T, y, x, 0.0f, rt);
    float uav = ru[1][1], vav = rv[1][1];
    float sig = sigma_at(y, x);
    const float hdt = 0.5f * DT;
    float un = ru[1][1] + hdt * (uav * cxv(ru) + vav * cyv(ru) + NU * cdv(ru));
    float vn = rv[1][1] + hdt * (uav * cxv(rv) + vav * cyv(rv) + NU * cdv(rv));
    float Tn = rt[1][1] + hdt * (uav * cxv(rt) + vav * cyv(rt) + AT * cdv(rt));
    float den = 1.0f + hdt * sig;
    un /= den; vn /= den;
    if (sig > 0.0f) Tn = 1.0f;
    size_t i = (size_t)y * NX + x;
    up[i] = un; vp[i] = vn; Tp[i] = Tn;
}

__global__ void corr_k(const float* __restrict__ u, const float* __restrict__ v,
                       const float* __restrict__ T,
                       const float* __restrict__ up, const float* __restrict__ vp,
                       const float* __restrict__ Tp,
                       float* __restrict__ us, float* __restrict__ vs,
                       float* __restrict__ oT,
                       float* __restrict__ obuu, float* __restrict__ obvv,
                       float* __restrict__ obTT) {
    int px = blockIdx.x * blockDim.x + threadIdx.x;
    int py = blockIdx.y;
    if (px >= PX) return;
    int y = py - 1, x = px - 1;
    int cy = min(max(y, 0), NY - 1), cx = min(max(x, 0), NX - 1);
    size_t o = (size_t)py * PX + px, s = (size_t)cy * NX + cx;
    obuu[o] = (px == 0) ? 1.5f : up[s];
    obvv[o] = (px == 0) ? 0.0f : vp[s];
    obTT[o] = (px == 0) ? 0.0f : Tp[s];
    if (y < 0 || y >= NY || x < 0 || x >= NX) return;
    float ru[3][3], rv[3][3], rt[3][3];
    g9(up, y, x, 1.5f, ru);
    g9(vp, y, x, 0.0f, rv);
    g9(Tp, y, x, 0.0f, rt);
    float uav = ru[1][1], vav = rv[1][1];
    float sig = sigma_at(y, x);
    size_t i = (size_t)y * NX + x;
    float un = u[i] + DT * (uav * cxv(ru) + vav * cyv(ru) + NU * cdv(ru));
    float vn = v[i] + DT * (uav * cxv(rv) + vav * cyv(rv) + NU * cdv(rv));
    float Tn = T[i] + DT * (uav * cxv(rt) + vav * cyv(rt) + AT * cdv(rt));
    float den = 1.0f + DT * sig;
    un /= den; vn /= den;
    if (sig > 0.0f) Tn = 1.0f;
    us[i] = un; vs[i] = vn; oT[i] = Tn;
}

__global__ void rhsdiv_k(const float* __restrict__ us, const float* __restrict__ vs,
                         float* __restrict__ rhs,
                         float* __restrict__ ouus, float* __restrict__ ovvs) {
    int px = blockIdx.x * blockDim.x + threadIdx.x;
    int py = blockIdx.y;
    if (px >= PX) return;
    int y = py - 1, x = px - 1;
    int cy = min(max(y, 0), NY - 1), cx = min(max(x, 0), NX - 1);
    size_t o = (size_t)py * PX + px, s = (size_t)cy * NX + cx;
    ouus[o] = (px == 0) ? 1.5f : us[s];
    ovvs[o] = (px == 0) ? 0.0f : vs[s];
    if (y < 0 || y >= NY || x < 0 || x >= NX) return;
    float ru[3][3], rv[3][3];
    g9(us, y, x, 1.5f, ru);
    g9(vs, y, x, 0.0f, rv);
    rhs[(size_t)y * NX + x] = (cxv(ru) + cyv(rv)) * (1.0f / DT);
}

__global__ void proj2_k(const float* __restrict__ us, const float* __restrict__ vs,
                        const float* __restrict__ p,
                        float* __restrict__ un, float* __restrict__ vn,
                        float* __restrict__ opp) {
    int px = blockIdx.x * blockDim.x + threadIdx.x;
    int py = blockIdx.y;
    if (px >= PX) return;
    int y = py - 1, x = px - 1;
    int cy = min(max(y, 0), NY - 1);
    opp[(size_t)py * PX + px] =
        (px == PX - 1) ? 0.0f : p[(size_t)cy * NX + max(x, 0)];
    if (y < 0 || y >= NY || x < 0 || x >= NX) return;
    float rp[3][3];
    g9p(p, y, x, rp);
    float sig = sigma_at(y, x);
    float den = 1.0f + DT * sig;
    size_t i = (size_t)y * NX + x;
    un[i] = (us[i] + cxv(rp) * DT) / den;
    vn[i] = (vs[i] + cyv(rp) * DT) / den;
}

// ---------------- register-resident Jacobi (lean sweep) ----------------------
// Whole-wave DPP neighbor fetch (correctness-proven rounds 10/14):
//   wave_shr:1 (0x138): lane i <- lane i-1 (WEST); lane 0 keeps old(=self)
//   wave_shl:1 (0x130): lane i <- lane i+1 (EAST); lane 63 keeps old(=self)
__device__ __forceinline__ float dpp_west64(float x) {
    int i = __float_as_int(x);
    return __int_as_float(__builtin_amdgcn_update_dpp(i, i, 0x138, 0xF, 0xF, false));
}
__device__ __forceinline__ float dpp_east64(float x) {
    int i = __float_as_int(x);
    return __int_as_float(__builtin_amdgcn_update_dpp(i, i, 0x130, 0xF, 0xF, false));
}

// One Jacobi sweep. rq[] is PRE-SCALED by 0.375. Update:
//   p' = 0.125*(sum9 - p) + rq375. Residual (EMIT) = (p - p')*8/3.
// N/S domain clamp: wave-uniform cs[] fix-up. W/E lane clamp: edge tiles only.
template <bool EDGE, bool EMIT>
__device__ __forceinline__ void jsweep(float (&p)[JR], const float (&rq)[JR - 2],
                                       bool fixN, bool fixS,
                                       bool wb, bool eb, int gy0, int gx,
                                       bool stp, float* __restrict__ res) {
    float cs[JR];
#pragma unroll
    for (int r = 0; r < JR; ++r) {
        float c = p[r];
        float w = dpp_west64(c);
        float e = dpp_east64(c);
        if (EDGE) {
            w = wb ? c : w;     // gx==0: west neighbor = self (edge clamp)
            e = eb ? 0.0f : e;  // gx==NX-1: east neighbor = 0 (outlet pad)
        }
        cs[r] = w + c + e;
    }
    if (fixN) cs[RN - 1] = cs[RN];
    if (fixS) cs[RS + 1] = cs[RS];
#pragma unroll
    for (int r = 1; r < JR - 1; ++r) {
        float s  = cs[r - 1] + cs[r] + cs[r + 1] - p[r];
        float pn = fmaf(0.125f, s, rq[r - 1]);
        if (EMIT) {
            if (r >= HALO && r < HALO + JCH && stp)
                res[(size_t)(gy0 + r) * NX + gx] = (p[r] - pn) * (8.0f / 3.0f);
        }
        p[r] = pn;
    }
}

// One full stage: load register tile from src, JK sweeps, store core to dst.
template <bool EDGE>
__device__ __forceinline__ void jstage_reg(const float* __restrict__ src,
                                           float* __restrict__ dst,
                                           float* __restrict__ res,
                                           const float (&rq)[JR - 2],
                                           bool fixN, bool fixS,
                                           int gy0, int gx, int cgx,
                                           bool wb, bool eb, bool stp) {
    float p[JR];
#pragma unroll
    for (int r = 0; r < JR; ++r) {
        int cy = min(max(gy0 + r, 0), NY - 1);
        p[r] = src[(size_t)cy * NX + cgx];
    }
#pragma unroll 1
    for (int j = 0; j < JK - 1; ++j)
        jsweep<EDGE, false>(p, rq, fixN, fixS, wb, eb, gy0, gx, stp, nullptr);
    if (res) jsweep<EDGE, true>(p, rq, fixN, fixS, wb, eb, gy0, gx, stp, res);
    else     jsweep<EDGE, false>(p, rq, fixN, fixS, wb, eb, gy0, gx, stp, nullptr);
    if (stp) {
#pragma unroll
        for (int r = HALO; r < HALO + JCH; ++r)
            dst[(size_t)(gy0 + r) * NX + gx] = p[r];
    }
}

// min-waves-per-EU = 1: allow high VGPR (p[48]+cs[48]+rq[46] live floats).
__global__ __launch_bounds__(64, 1)
void jacobi_reg(const float* __restrict__ src, const float* __restrict__ rhs,
                float* __restrict__ dst, float* __restrict__ res) {
    const int wid = blockIdx.x;               // one 64-lane wave per block
    const int tx = wid % JTX, ty = wid / JTX;
    const int lane = threadIdx.x;             // 0..63
    const int gx = tx * JCW - HALO + lane;    // this lane's column
    const int gy0 = ty * JCH - HALO;          // tile top row
    const int cgx = min(max(gx, 0), NX - 1);  // clamped load column
    const bool wb = (gx == 0);                // west domain edge (clamp)
    const bool eb = (gx == NX - 1);           // east domain edge (outlet 0)
    const bool stp = (lane >= HALO) && (lane < HALO + JCW) && (gx < NX);
    const bool fixN = (ty == 0), fixS = (ty == JTY - 1);

    float rq[JR - 2];                          // 0.375 * rhs (pre-scaled)
#pragma unroll
    for (int r = 1; r < JR - 1; ++r) {
        int cy = min(max(gy0 + r, 0), NY - 1);
        rq[r - 1] = 0.375f * rhs[(size_t)cy * NX + cgx];
    }
    if (tx == 0 || tx == JTX - 1)
        jstage_reg<true>(src, dst, res, rq, fixN, fixS, gy0, gx, cgx, wb, eb, stp);
    else
        jstage_reg<false>(src, dst, res, rq, fixN, fixS, gy0, gx, cgx, wb, eb, stp);
}

extern "C" void kernel_launch(void* const* d_in, const int* in_sizes, int n_in,
                              void* d_out, int out_size, void* d_ws, size_t ws_size,
                              hipStream_t stream) {
    const float* u = (const float*)d_in[0];
    const float* v = (const float*)d_in[1];
    const float* p = (const float*)d_in[2];
    const float* T = (const float*)d_in[3];

    float* out = (float*)d_out;
    float* o_u   = out;
    float* o_v   = out + (size_t)NI;
    float* o_p   = out + 2 * (size_t)NI;
    float* o_T   = out + 3 * (size_t)NI;
    float* o_uus = out + 4 * (size_t)NI;
    float* o_vvs = o_uus + (size_t)NP;
    float* o_pp  = o_uus + 2 * (size_t)NP;
    float* o_TT  = o_uus + 3 * (size_t)NP;
    float* o_buu = o_uus + 4 * (size_t)NP;
    float* o_bvv = o_uus + 5 * (size_t)NP;
    float* o_bTT = o_uus + 6 * (size_t)NP;
    float* o_res = o_uus + 7 * (size_t)NP;

    float* w  = (float*)d_ws;
    float* s_up  = w;                      // u_pred -> jacobi ping A
    float* s_vp  = w + (size_t)NI;         // v_pred -> jacobi ping B
    float* s_Tp  = w + 2 * (size_t)NI;     // T_pred -> rhs
    float* s_us  = w + 3 * (size_t)NI;     // u_star
    float* s_vs  = w + 4 * (size_t)NI;     // v_star
    float* s_rhs = s_Tp;
    float* pA = s_up;
    float* pB = s_vp;

    dim3 blk(256, 1, 1);
    dim3 gp((PX + 255) / 256, PY, 1);
    dim3 gj(JWAVES, 1, 1);
    dim3 bj(64, 1, 1);

    pred_k<<<gp, blk, 0, stream>>>(u, v, T, s_up, s_vp, s_Tp, o_TT);
    corr_k<<<gp, blk, 0, stream>>>(u, v, T, s_up, s_vp, s_Tp,
                                   s_us, s_vs, o_T, o_buu, o_bvv, o_bTT);
    rhsdiv_k<<<gp, blk, 0, stream>>>(s_us, s_vs, s_rhs, o_uus, o_vvs);

    // 40 Jacobi iterations = 5 stream-ordered launches x 8 register-resident
    jacobi_reg<<<gj, bj, 0, stream>>>(p,  s_rhs, pA,  nullptr);
    jacobi_reg<<<gj, bj, 0, stream>>>(pA, s_rhs, pB,  nullptr);
    jacobi_reg<<<gj, bj, 0, stream>>>(pB, s_rhs, pA,  nullptr);
    jacobi_reg<<<gj, bj, 0, stream>>>(pA, s_rhs, pB,  nullptr);
    jacobi_reg<<<gj, bj, 0, stream>>>(pB, s_rhs, o_p, o_res);

    proj2_k<<<gp, blk, 0, stream>>>(s_us, s_vs, o_p, o_u, o_v, o_pp);
}

// Round 19
// 106.202 us; speedup vs baseline: 1.1261x; 1.0450x over previous
//
#include <hip/hip_runtime.h>

// One timestep of the AI4CFD semicircle-cylinder NS solver.
// Grid: interior NY x NX = 160 x 6600, padded PY x PX = 162 x 6602.
// Round 19: r18 lean register Jacobi, 5 stages -> 3 stages {13,13,14}.
// HALO=14, JCW=36, JCH=32 -> 920 waves (<=1024 SIMDs, no 2-wave tail).
// Rationale: stage ~= fix(large) + c*rows; boundaries dominate compute.

namespace {
constexpr int NY = 160, NX = 6600, PY = 162, PX = 6602;
constexpr int NI = NY * NX;   // 1,056,000
constexpr int NP = PY * PX;   // 1,069,524
constexpr float DT  = 0.005f;
constexpr float NU  = 0.01f;          // 1/RE
constexpr float AT  = 1.0f / 70.0f;   // 1/(RE*PR)

constexpr int HALO = 14;              // >= max sweeps per stage (14)
constexpr int JCH  = 32;              // core rows per wave (160/32 = 5)
constexpr int JCW  = 64 - 2 * HALO;   // 36 core cols per wave
constexpr int JR   = JCH + 2 * HALO;  // 60 register rows
constexpr int JTX  = (NX + JCW - 1) / JCW;  // 184
constexpr int JTY  = NY / JCH;        // 5
constexpr int JWAVES = JTX * JTY;     // 920  (<= 1024 SIMDs)
constexpr int RN   = HALO;            // row where gy==0 occurs (ty==0)
constexpr int RS   = JR - HALO - 1;   // row where gy==NY-1 occurs (ty==JTY-1)
}

// Brinkman penalization field: semicircle at (x=1800, y=80), R=20, x>=1800.
__device__ __forceinline__ float sigma_at(int y, int x) {
    int ddx = x - 1800, ddy = y - 80;
    return ((ddx * ddx + ddy * ddy <= 400) && (x >= 1800)) ? 1.0e6f : 0.0f;
}

// ---- stencil weights ----
__device__ __forceinline__ float cxv(const float r[3][3]) {   // w_xadv
    return (r[0][0] - r[0][2] + 4.0f * (r[1][0] - r[1][2]) + r[2][0] - r[2][2])
           * (1.0f / 12.0f);
}
__device__ __forceinline__ float cyv(const float r[3][3]) {   // w_yadv
    return (r[0][0] + 4.0f * r[0][1] + r[0][2]
            - r[2][0] - 4.0f * r[2][1] - r[2][2]) * (1.0f / 12.0f);
}
__device__ __forceinline__ float cdv(const float r[3][3]) {   // w_diff
    return (r[0][0] + r[0][1] + r[0][2]
            + r[1][0] - 8.0f * r[1][1] + r[1][2]
            + r[2][0] + r[2][1] + r[2][2]) * (1.0f / 3.0f);
}

// g9 / g9p gathers for the aux kernels.
__device__ __forceinline__ void g9(const float* __restrict__ a, int y, int x,
                                   float lc, float r[3][3]) {
    int ym = max(y - 1, 0), yp = min(y + 1, NY - 1);
    int xp = min(x + 1, NX - 1);
    const float* r0 = a + (size_t)ym * NX;
    const float* r1 = a + (size_t)y  * NX;
    const float* r2 = a + (size_t)yp * NX;
    if (x == 0) { r[0][0] = lc; r[1][0] = lc; r[2][0] = lc; }
    else        { r[0][0] = r0[x-1]; r[1][0] = r1[x-1]; r[2][0] = r2[x-1]; }
    r[0][1] = r0[x]; r[0][2] = r0[xp];
    r[1][1] = r1[x]; r[1][2] = r1[xp];
    r[2][1] = r2[x]; r[2][2] = r2[xp];
}
__device__ __forceinline__ void g9p(const float* __restrict__ a, int y, int x,
                                    float r[3][3]) {
    int ym = max(y - 1, 0), yp = min(y + 1, NY - 1);
    int xm = max(x - 1, 0);
    bool rb = (x == NX - 1);
    const float* r0 = a + (size_t)ym * NX;
    const float* r1 = a + (size_t)y  * NX;
    const float* r2 = a + (size_t)yp * NX;
    r[0][0] = r0[xm]; r[0][1] = r0[x]; r[0][2] = rb ? 0.0f : r0[x+1];
    r[1][0] = r1[xm]; r[1][1] = r1[x]; r[1][2] = rb ? 0.0f : r1[x+1];
    r[2][0] = r2[xm]; r[2][1] = r2[x]; r[2][2] = rb ? 0.0f : r2[x+1];
}

// ---------------- aux kernels (unchanged, proven in rounds 1-3/7/9) ------------
__global__ void pred_k(const float* __restrict__ u, const float* __restrict__ v,
                       const float* __restrict__ T,
                       float* __restrict__ up, float* __restrict__ vp,
                       float* __restrict__ Tp, float* __restrict__ oTT) {
    int px = blockIdx.x * blockDim.x + threadIdx.x;
    int py = blockIdx.y;
    if (px >= PX) return;
    int y = py - 1, x = px - 1;
    int cy = min(max(y, 0), NY - 1), cx = min(max(x, 0), NX - 1);
    oTT[(size_t)py * PX + px] = (px == 0) ? 0.0f : T[(size_t)cy * NX + cx];
    if (y < 0 || y >= NY || x < 0 || x >= NX) return;
    float ru[3][3], rv[3][3], rt[3][3];
    g9(u, y, x, 1.5f, ru);
    g9(v, y, x, 0.0f, rv);
    g9(T, y, x, 0.0f, rt);
    float uav = ru[1][1], vav = rv[1][1];
    float sig = sigma_at(y, x);
    const float hdt = 0.5f * DT;
    float un = ru[1][1] + hdt * (uav * cxv(ru) + vav * cyv(ru) + NU * cdv(ru));
    float vn = rv[1][1] + hdt * (uav * cxv(rv) + vav * cyv(rv) + NU * cdv(rv));
    float Tn = rt[1][1] + hdt * (uav * cxv(rt) + vav * cyv(rt) + AT * cdv(rt));
    float den = 1.0f + hdt * sig;
    un /= den; vn /= den;
    if (sig > 0.0f) Tn = 1.0f;
    size_t i = (size_t)y * NX + x;
    up[i] = un; vp[i] = vn; Tp[i] = Tn;
}

__global__ void corr_k(const float* __restrict__ u, const float* __restrict__ v,
                       const float* __restrict__ T,
                       const float* __restrict__ up, const float* __restrict__ vp,
                       const float* __restrict__ Tp,
                       float* __restrict__ us, float* __restrict__ vs,
                       float* __restrict__ oT,
                       float* __restrict__ obuu, float* __restrict__ obvv,
                       float* __restrict__ obTT) {
    int px = blockIdx.x * blockDim.x + threadIdx.x;
    int py = blockIdx.y;
    if (px >= PX) return;
    int y = py - 1, x = px - 1;
    int cy = min(max(y, 0), NY - 1), cx = min(max(x, 0), NX - 1);
    size_t o = (size_t)py * PX + px, s = (size_t)cy * NX + cx;
    obuu[o] = (px == 0) ? 1.5f : up[s];
    obvv[o] = (px == 0) ? 0.0f : vp[s];
    obTT[o] = (px == 0) ? 0.0f : Tp[s];
    if (y < 0 || y >= NY || x < 0 || x >= NX) return;
    float ru[3][3], rv[3][3], rt[3][3];
    g9(up, y, x, 1.5f, ru);
    g9(vp, y, x, 0.0f, rv);
    g9(Tp, y, x, 0.0f, rt);
    float uav = ru[1][1], vav = rv[1][1];
    float sig = sigma_at(y, x);
    size_t i = (size_t)y * NX + x;
    float un = u[i] + DT * (uav * cxv(ru) + vav * cyv(ru) + NU * cdv(ru));
    float vn = v[i] + DT * (uav * cxv(rv) + vav * cyv(rv) + NU * cdv(rv));
    float Tn = T[i] + DT * (uav * cxv(rt) + vav * cyv(rt) + AT * cdv(rt));
    float den = 1.0f + DT * sig;
    un /= den; vn /= den;
    if (sig > 0.0f) Tn = 1.0f;
    us[i] = un; vs[i] = vn; oT[i] = Tn;
}

__global__ void rhsdiv_k(const float* __restrict__ us, const float* __restrict__ vs,
                         float* __restrict__ rhs,
                         float* __restrict__ ouus, float* __restrict__ ovvs) {
    int px = blockIdx.x * blockDim.x + threadIdx.x;
    int py = blockIdx.y;
    if (px >= PX) return;
    int y = py - 1, x = px - 1;
    int cy = min(max(y, 0), NY - 1), cx = min(max(x, 0), NX - 1);
    size_t o = (size_t)py * PX + px, s = (size_t)cy * NX + cx;
    ouus[o] = (px == 0) ? 1.5f : us[s];
    ovvs[o] = (px == 0) ? 0.0f : vs[s];
    if (y < 0 || y >= NY || x < 0 || x >= NX) return;
    float ru[3][3], rv[3][3];
    g9(us, y, x, 1.5f, ru);
    g9(vs, y, x, 0.0f, rv);
    rhs[(size_t)y * NX + x] = (cxv(ru) + cyv(rv)) * (1.0f / DT);
}

__global__ void proj2_k(const float* __restrict__ us, const float* __restrict__ vs,
                        const float* __restrict__ p,
                        float* __restrict__ un, float* __restrict__ vn,
                        float* __restrict__ opp) {
    int px = blockIdx.x * blockDim.x + threadIdx.x;
    int py = blockIdx.y;
    if (px >= PX) return;
    int y = py - 1, x = px - 1;
    int cy = min(max(y, 0), NY - 1);
    opp[(size_t)py * PX + px] =
        (px == PX - 1) ? 0.0f : p[(size_t)cy * NX + max(x, 0)];
    if (y < 0 || y >= NY || x < 0 || x >= NX) return;
    float rp[3][3];
    g9p(p, y, x, rp);
    float sig = sigma_at(y, x);
    float den = 1.0f + DT * sig;
    size_t i = (size_t)y * NX + x;
    un[i] = (us[i] + cxv(rp) * DT) / den;
    vn[i] = (vs[i] + cyv(rp) * DT) / den;
}

// ---------------- register-resident Jacobi (lean sweep) ----------------------
// Whole-wave DPP neighbor fetch (correctness-proven rounds 10/14/16/18):
//   wave_shr:1 (0x138): lane i <- lane i-1 (WEST); lane 0 keeps old(=self)
//   wave_shl:1 (0x130): lane i <- lane i+1 (EAST); lane 63 keeps old(=self)
__device__ __forceinline__ float dpp_west64(float x) {
    int i = __float_as_int(x);
    return __int_as_float(__builtin_amdgcn_update_dpp(i, i, 0x138, 0xF, 0xF, false));
}
__device__ __forceinline__ float dpp_east64(float x) {
    int i = __float_as_int(x);
    return __int_as_float(__builtin_amdgcn_update_dpp(i, i, 0x130, 0xF, 0xF, false));
}

// One Jacobi sweep. rq[] is PRE-SCALED by 0.375. Update:
//   p' = 0.125*(sum9 - p) + rq375. Residual (EMIT) = (p - p')*8/3.
// N/S domain clamp: wave-uniform cs[] fix-up. W/E lane clamp: edge tiles only.
template <bool EDGE, bool EMIT>
__device__ __forceinline__ void jsweep(float (&p)[JR], const float (&rq)[JR - 2],
                                       bool fixN, bool fixS,
                                       bool wb, bool eb, int gy0, int gx,
                                       bool stp, float* __restrict__ res) {
    float cs[JR];
#pragma unroll
    for (int r = 0; r < JR; ++r) {
        float c = p[r];
        float w = dpp_west64(c);
        float e = dpp_east64(c);
        if (EDGE) {
            w = wb ? c : w;     // gx==0: west neighbor = self (edge clamp)
            e = eb ? 0.0f : e;  // gx==NX-1: east neighbor = 0 (outlet pad)
        }
        cs[r] = w + c + e;
    }
    if (fixN) cs[RN - 1] = cs[RN];
    if (fixS) cs[RS + 1] = cs[RS];
#pragma unroll
    for (int r = 1; r < JR - 1; ++r) {
        float s  = cs[r - 1] + cs[r] + cs[r + 1] - p[r];
        float pn = fmaf(0.125f, s, rq[r - 1]);
        if (EMIT) {
            if (r >= HALO && r < HALO + JCH && stp)
                res[(size_t)(gy0 + r) * NX + gx] = (p[r] - pn) * (8.0f / 3.0f);
        }
        p[r] = pn;
    }
}

// One full stage: load register tile from src, nswp sweeps, store core to dst.
template <bool EDGE>
__device__ __forceinline__ void jstage_reg(const float* __restrict__ src,
                                           float* __restrict__ dst,
                                           float* __restrict__ res,
                                           const float (&rq)[JR - 2],
                                           int nswp, bool fixN, bool fixS,
                                           int gy0, int gx, int cgx,
                                           bool wb, bool eb, bool stp) {
    float p[JR];
#pragma unroll
    for (int r = 0; r < JR; ++r) {
        int cy = min(max(gy0 + r, 0), NY - 1);
        p[r] = src[(size_t)cy * NX + cgx];
    }
#pragma unroll 1
    for (int j = 0; j < nswp - 1; ++j)
        jsweep<EDGE, false>(p, rq, fixN, fixS, wb, eb, gy0, gx, stp, nullptr);
    if (res) jsweep<EDGE, true>(p, rq, fixN, fixS, wb, eb, gy0, gx, stp, res);
    else     jsweep<EDGE, false>(p, rq, fixN, fixS, wb, eb, gy0, gx, stp, nullptr);
    if (stp) {
#pragma unroll
        for (int r = HALO; r < HALO + JCH; ++r)
            dst[(size_t)(gy0 + r) * NX + gx] = p[r];
    }
}

// min-waves-per-EU = 1: allow high VGPR (p[60]+rq[58]+cs window live).
__global__ __launch_bounds__(64, 1)
void jacobi_reg(const float* __restrict__ src, const float* __restrict__ rhs,
                float* __restrict__ dst, float* __restrict__ res, int nswp) {
    const int wid = blockIdx.x;               // one 64-lane wave per block
    const int tx = wid % JTX, ty = wid / JTX;
    const int lane = threadIdx.x;             // 0..63
    const int gx = tx * JCW - HALO + lane;    // this lane's column
    const int gy0 = ty * JCH - HALO;          // tile top row
    const int cgx = min(max(gx, 0), NX - 1);  // clamped load column
    const bool wb = (gx == 0);                // west domain edge (clamp)
    const bool eb = (gx == NX - 1);           // east domain edge (outlet 0)
    const bool stp = (lane >= HALO) && (lane < HALO + JCW) && (gx < NX);
    const bool fixN = (ty == 0), fixS = (ty == JTY - 1);

    float rq[JR - 2];                          // 0.375 * rhs (pre-scaled)
#pragma unroll
    for (int r = 1; r < JR - 1; ++r) {
        int cy = min(max(gy0 + r, 0), NY - 1);
        rq[r - 1] = 0.375f * rhs[(size_t)cy * NX + cgx];
    }
    if (tx == 0 || tx == JTX - 1)
        jstage_reg<true>(src, dst, res, rq, nswp, fixN, fixS, gy0, gx, cgx, wb, eb, stp);
    else
        jstage_reg<false>(src, dst, res, rq, nswp, fixN, fixS, gy0, gx, cgx, wb, eb, stp);
}

extern "C" void kernel_launch(void* const* d_in, const int* in_sizes, int n_in,
                              void* d_out, int out_size, void* d_ws, size_t ws_size,
                              hipStream_t stream) {
    const float* u = (const float*)d_in[0];
    const float* v = (const float*)d_in[1];
    const float* p = (const float*)d_in[2];
    const float* T = (const float*)d_in[3];

    float* out = (float*)d_out;
    float* o_u   = out;
    float* o_v   = out + (size_t)NI;
    float* o_p   = out + 2 * (size_t)NI;
    float* o_T   = out + 3 * (size_t)NI;
    float* o_uus = out + 4 * (size_t)NI;
    float* o_vvs = o_uus + (size_t)NP;
    float* o_pp  = o_uus + 2 * (size_t)NP;
    float* o_TT  = o_uus + 3 * (size_t)NP;
    float* o_buu = o_uus + 4 * (size_t)NP;
    float* o_bvv = o_uus + 5 * (size_t)NP;
    float* o_bTT = o_uus + 6 * (size_t)NP;
    float* o_res = o_uus + 7 * (size_t)NP;

    float* w  = (float*)d_ws;
    float* s_up  = w;                      // u_pred -> jacobi ping A
    float* s_vp  = w + (size_t)NI;         // v_pred -> jacobi ping B
    float* s_Tp  = w + 2 * (size_t)NI;     // T_pred -> rhs
    float* s_us  = w + 3 * (size_t)NI;     // u_star
    float* s_vs  = w + 4 * (size_t)NI;     // v_star
    float* s_rhs = s_Tp;
    float* pA = s_up;
    float* pB = s_vp;

    dim3 blk(256, 1, 1);
    dim3 gp((PX + 255) / 256, PY, 1);
    dim3 gj(JWAVES, 1, 1);
    dim3 bj(64, 1, 1);

    pred_k<<<gp, blk, 0, stream>>>(u, v, T, s_up, s_vp, s_Tp, o_TT);
    corr_k<<<gp, blk, 0, stream>>>(u, v, T, s_up, s_vp, s_Tp,
                                   s_us, s_vs, o_T, o_buu, o_bvv, o_bTT);
    rhsdiv_k<<<gp, blk, 0, stream>>>(s_us, s_vs, s_rhs, o_uus, o_vvs);

    // 40 Jacobi iterations = 3 stream-ordered stages x {13,13,14}
    jacobi_reg<<<gj, bj, 0, stream>>>(p,  s_rhs, pA,  nullptr, 13);
    jacobi_reg<<<gj, bj, 0, stream>>>(pA, s_rhs, pB,  nullptr, 13);
    jacobi_reg<<<gj, bj, 0, stream>>>(pB, s_rhs, o_p, o_res,   14);

    proj2_k<<<gp, blk, 0, stream>>>(s_us, s_vs, o_p, o_u, o_v, o_pp);
}